// Round 13
// baseline (842.407 us; speedup 1.0000x reference)
//
#include <hip/hip_runtime.h>

#define NEG 0.2f
#define BSH 8                       // 256 nodes per bucket
#define CHB 8192                    // edges per binning block
__device__ __forceinline__ float lrelu(float x){ return fmaxf(x, NEG*x); }

__device__ __forceinline__ float bf2f(unsigned short u){
  union{unsigned int i; float f;} v; v.i = ((unsigned int)u)<<16; return v.f;
}
__device__ __forceinline__ unsigned short f2bf(float f){
  union{float f; unsigned int i;} v; v.f = f;
  unsigned int b = v.i;
  b += 0x7FFFu + ((b>>16)&1u);   // round-to-nearest-even
  return (unsigned short)(b>>16);
}

// ---------------- CSR build: block-staged two-level counting sort ----------------
__global__ __launch_bounds__(256) void zero_kernel(int* __restrict__ p, int n){
  int i = blockIdx.x*256 + threadIdx.x;
  if (i < n) p[i] = 0;
}

__global__ __launch_bounds__(256) void bin_count(const int* __restrict__ dstv, int* __restrict__ bcnt,
                                                 int E, int NB){
  __shared__ int lh[256];
  int tid = threadIdx.x;
  lh[tid] = 0;
  __syncthreads();
  int e0 = blockIdx.x * CHB;
  int e1 = min(e0 + CHB, E);
  for (int i = e0 + tid; i < e1; i += 256)
    atomicAdd(&lh[dstv[i] >> BSH], 1);
  __syncthreads();
  if (tid < NB && lh[tid] > 0) atomicAdd(&bcnt[tid], lh[tid]);
}

__global__ __launch_bounds__(256) void scan_kernel(const int* __restrict__ counts, int* __restrict__ offs,
                                                   int* __restrict__ cursor, int n){
  __shared__ int wsum[4];
  __shared__ int carry_s;
  int tid = threadIdx.x, lane = tid & 63, wv = tid >> 6;
  if (tid == 0) carry_s = 0;
  __syncthreads();
  const int CH = 2048;
  int nch = (n + CH - 1)/CH;
  for (int ch=0; ch<nch; ++ch){
    int base_i = ch*CH + tid*8;
    int v[8], pre[8];
    #pragma unroll
    for (int j=0;j<8;++j){ int i=base_i+j; v[j]=(i<n)?counts[i]:0; }
    int t=0;
    #pragma unroll
    for (int j=0;j<8;++j){ pre[j]=t; t+=v[j]; }
    int incl=t;
    #pragma unroll
    for (int m=1;m<64;m<<=1){ int u=__shfl_up(incl,m); if(lane>=m) incl+=u; }
    int wexcl = incl - t;
    if (lane==63) wsum[wv]=incl;
    __syncthreads();
    int wbase=0;
    for (int w2=0;w2<wv;++w2) wbase+=wsum[w2];
    int total = wsum[0]+wsum[1]+wsum[2]+wsum[3];
    int base = carry_s + wbase + wexcl;
    #pragma unroll
    for (int j=0;j<8;++j){ int i=base_i+j; if(i<n){ int val=base+pre[j]; offs[i]=val; cursor[i]=val; } }
    __syncthreads();
    if (tid==0) carry_s += total;
    __syncthreads();
  }
  if (tid==0) offs[n]=carry_s;
}

__global__ __launch_bounds__(256) void bin_scatter(const int* __restrict__ srcv, const int* __restrict__ dstv,
                                                   int* __restrict__ bcur, int2* __restrict__ pairs,
                                                   int E, int NB){
  __shared__ int lh[256];
  __shared__ int lcur[256];
  int tid = threadIdx.x;
  lh[tid] = 0;
  __syncthreads();
  int e0 = blockIdx.x * CHB;
  int e1 = min(e0 + CHB, E);
  for (int i = e0 + tid; i < e1; i += 256)
    atomicAdd(&lh[dstv[i] >> BSH], 1);
  __syncthreads();
  if (tid < NB){
    int c = lh[tid];
    lcur[tid] = (c > 0) ? atomicAdd(&bcur[tid], c) : 0;
  }
  __syncthreads();
  for (int i = e0 + tid; i < e1; i += 256){
    int s = srcv[i], d = dstv[i];
    int p = atomicAdd(&lcur[d >> BSH], 1);
    pairs[p] = make_int2(s, d);
  }
}

__global__ __launch_bounds__(256) void bucket_finalize(const int2* __restrict__ pairs,
                                                       const int* __restrict__ bbase,
                                                       int* __restrict__ offs, int* __restrict__ csr,
                                                       int N, int E){
  __shared__ int lh[256];
  __shared__ int lcur[256];
  __shared__ int wsum[4];
  int b = blockIdx.x;
  int base = bbase[b], end = bbase[b+1];
  int node0 = b << BSH;
  int tid = threadIdx.x, lane = tid & 63, wv = tid >> 6;
  lh[tid] = 0;
  if (b == 0 && tid == 0) offs[N] = E;
  __syncthreads();
  for (int i = base + tid; i < end; i += 256)
    atomicAdd(&lh[pairs[i].y - node0], 1);
  __syncthreads();
  {
    int v = lh[tid];
    int incl = v;
    #pragma unroll
    for (int m=1;m<64;m<<=1){ int u=__shfl_up(incl,m); if(lane>=m) incl+=u; }
    if (lane==63) wsum[wv]=incl;
    __syncthreads();
    int wbase=0;
    for (int w2=0;w2<wv;++w2) wbase+=wsum[w2];
    int excl = wbase + incl - v;
    lcur[tid] = base + excl;
    int node = node0 + tid;
    if (node < N) offs[node] = base + excl;
  }
  __syncthreads();
  for (int i = base + tid; i < end; i += 256){
    int2 pr = pairs[i];
    int p = atomicAdd(&lcur[pr.y - node0], 1);
    csr[p] = pr.x;
  }
}

// ---------------- GEMM fused with alpha dots + bf16 cast ----------------
// single-buffered chunked W staging (16KB LDS), TR rows/thread
template<int NOUT, int TR, int HEADS>
__global__ __launch_bounds__(256) void gemm_fused(const float* __restrict__ X, const float* __restrict__ W,
    const float* __restrict__ a_s, const float* __restrict__ a_d,
    unsigned short* __restrict__ hb, float* __restrict__ as_, float* __restrict__ ad_, int n){
  constexpr int NC = NOUT / 8;          // threads per row
  constexpr int RG = 256 / NC;          // row groups
  constexpr int BM = RG * TR;           // rows per block
  constexpr int CHK = (NOUT > 64) ? 32 : 128;   // k rows per chunk (16KB LDS)
  constexpr int NCH = 128 / CHK;
  __shared__ float Wl[CHK * NOUT];
  int tid = threadIdx.x;
  int cg = tid % NC;
  int rg = tid / NC;
  int lane = tid & 63;
  int row0 = blockIdx.x * BM + rg * TR;
  const float4* Wv = (const float4*)W;
  const float4* Xv = (const float4*)X;
  float acc[TR][8];
  #pragma unroll
  for (int r=0;r<TR;++r)
    #pragma unroll
    for (int c=0;c<8;++c) acc[r][c]=0.f;
  for (int ch = 0; ch < NCH; ++ch){
    if (ch) __syncthreads();
    for (int i = tid; i < CHK*NOUT/4; i += 256)
      ((float4*)Wl)[i] = Wv[ch*(CHK*NOUT/4) + i];
    __syncthreads();
    for (int k4i = 0; k4i < CHK/4; ++k4i){
      int k4 = ch*(CHK/4) + k4i;
      float4 xv[TR];
      #pragma unroll
      for (int r = 0; r < TR; ++r){
        int row = row0 + r;
        xv[r] = (row < n) ? Xv[(size_t)row*32 + k4] : make_float4(0.f,0.f,0.f,0.f);
      }
      #pragma unroll
      for (int kk = 0; kk < 4; ++kk){
        float wv[8];
        #pragma unroll
        for (int c = 0; c < 8; ++c) wv[c] = Wl[(k4i*4+kk)*NOUT + cg*8 + c];
        #pragma unroll
        for (int r = 0; r < TR; ++r){
          float xr = (kk==0)?xv[r].x:(kk==1)?xv[r].y:(kk==2)?xv[r].z:xv[r].w;
          #pragma unroll
          for (int c = 0; c < 8; ++c) acc[r][c] = fmaf(xr, wv[c], acc[r][c]);
        }
      }
    }
  }
  // epilogue: bf16 row + per-head alpha dots (head = 32 ch = 4 threads)
  float asl[8], adl[8];
  #pragma unroll
  for (int c=0;c<8;++c){ asl[c]=a_s[cg*8+c]; adl[c]=a_d[cg*8+c]; }
  #pragma unroll
  for (int r = 0; r < TR; ++r){
    int row = row0 + r;
    float s=0.f, dd=0.f;
    #pragma unroll
    for (int c=0;c<8;++c){ s = fmaf(acc[r][c], asl[c], s); dd = fmaf(acc[r][c], adl[c], dd); }
    s  += __shfl_xor(s,1);  s  += __shfl_xor(s,2);
    dd += __shfl_xor(dd,1); dd += __shfl_xor(dd,2);
    if (HEADS == 4){
      int base = lane & ~15;
      float s0=__shfl(s,base),  s1=__shfl(s,base+4),  s2=__shfl(s,base+8),  s3=__shfl(s,base+12);
      float d0=__shfl(dd,base), d1=__shfl(dd,base+4), d2=__shfl(dd,base+8), d3=__shfl(dd,base+12);
      if (row < n && cg == 0){
        ((float4*)as_)[row] = make_float4(s0,s1,s2,s3);
        ((float4*)ad_)[row] = make_float4(d0,d1,d2,d3);
      }
    } else {
      if (row < n && (lane&3) == 0){ as_[row] = s; ad_[row] = dd; }
    }
    if (row < n){
      ushort4 p0, p1;
      p0.x=f2bf(acc[r][0]); p0.y=f2bf(acc[r][1]); p0.z=f2bf(acc[r][2]); p0.w=f2bf(acc[r][3]);
      p1.x=f2bf(acc[r][4]); p1.y=f2bf(acc[r][5]); p1.z=f2bf(acc[r][6]); p1.w=f2bf(acc[r][7]);
      *(ushort4*)&hb[(size_t)row*NOUT + cg*8 + 0] = p0;
      *(ushort4*)&hb[(size_t)row*NOUT + cg*8 + 4] = p1;
    }
  }
}

__device__ __forceinline__ float sel4(int hh, float4 v){
  return (hh&2) ? ((hh&1)?v.w:v.z) : ((hh&1)?v.y:v.x);
}

// ---------------- aggregation, 4 heads x 32 ch: half-wave per edge, bf16 messages ----------------
__global__ __launch_bounds__(256) void agg_h4(const unsigned short* __restrict__ hb,
    const float4* __restrict__ as_, const float4* __restrict__ ad_,
    const int* __restrict__ offs, const int* __restrict__ csr,
    const float* __restrict__ bias, float* __restrict__ hout, int n){
  int wid = (blockIdx.x*256 + threadIdx.x) >> 6;
  int lane = threadIdx.x & 63;
  if (wid >= n) return;
  const int d = wid;
  float4 ad4 = ad_[d];
  float4 asd = as_[d];
  int r0 = offs[d], r1 = offs[d+1];
  int half = lane >> 5;
  int cl = lane & 31;        // channel group -> 4 channels
  int hh = cl >> 3;          // head
  float adh = sel4(hh, ad4);
  float asv = sel4(hh, asd);
  float acc0=0.f, acc1=0.f, acc2=0.f, acc3=0.f, den=0.f;
  if (half == 0){
    float w = __expf(lrelu(asv+adh));
    ushort4 hv = *(const ushort4*)&hb[(size_t)d*128 + 4*cl];
    acc0 = w*bf2f(hv.x); acc1 = w*bf2f(hv.y); acc2 = w*bf2f(hv.z); acc3 = w*bf2f(hv.w); den = w;
  }
  int e = r0 + half;
  for (; e+14 < r1; e += 16){
    int s0=csr[e],   s1=csr[e+2],  s2=csr[e+4],  s3=csr[e+6];
    int s4=csr[e+8], s5=csr[e+10], s6=csr[e+12], s7=csr[e+14];
    float4 a0=as_[s0], a1=as_[s1], a2=as_[s2], a3=as_[s3];
    float4 a4=as_[s4], a5=as_[s5], a6=as_[s6], a7=as_[s7];
    ushort4 h0=*(const ushort4*)&hb[(size_t)s0*128+4*cl];
    ushort4 h1=*(const ushort4*)&hb[(size_t)s1*128+4*cl];
    ushort4 h2=*(const ushort4*)&hb[(size_t)s2*128+4*cl];
    ushort4 h3=*(const ushort4*)&hb[(size_t)s3*128+4*cl];
    ushort4 h4=*(const ushort4*)&hb[(size_t)s4*128+4*cl];
    ushort4 h5=*(const ushort4*)&hb[(size_t)s5*128+4*cl];
    ushort4 h6=*(const ushort4*)&hb[(size_t)s6*128+4*cl];
    ushort4 h7=*(const ushort4*)&hb[(size_t)s7*128+4*cl];
    float w0=__expf(lrelu(sel4(hh,a0)+adh));
    float w1=__expf(lrelu(sel4(hh,a1)+adh));
    float w2=__expf(lrelu(sel4(hh,a2)+adh));
    float w3=__expf(lrelu(sel4(hh,a3)+adh));
    float w4=__expf(lrelu(sel4(hh,a4)+adh));
    float w5=__expf(lrelu(sel4(hh,a5)+adh));
    float w6=__expf(lrelu(sel4(hh,a6)+adh));
    float w7=__expf(lrelu(sel4(hh,a7)+adh));
    acc0=fmaf(w0,bf2f(h0.x),acc0); acc1=fmaf(w0,bf2f(h0.y),acc1); acc2=fmaf(w0,bf2f(h0.z),acc2); acc3=fmaf(w0,bf2f(h0.w),acc3); den+=w0;
    acc0=fmaf(w1,bf2f(h1.x),acc0); acc1=fmaf(w1,bf2f(h1.y),acc1); acc2=fmaf(w1,bf2f(h1.z),acc2); acc3=fmaf(w1,bf2f(h1.w),acc3); den+=w1;
    acc0=fmaf(w2,bf2f(h2.x),acc0); acc1=fmaf(w2,bf2f(h2.y),acc1); acc2=fmaf(w2,bf2f(h2.z),acc2); acc3=fmaf(w2,bf2f(h2.w),acc3); den+=w2;
    acc0=fmaf(w3,bf2f(h3.x),acc0); acc1=fmaf(w3,bf2f(h3.y),acc1); acc2=fmaf(w3,bf2f(h3.z),acc2); acc3=fmaf(w3,bf2f(h3.w),acc3); den+=w3;
    acc0=fmaf(w4,bf2f(h4.x),acc0); acc1=fmaf(w4,bf2f(h4.y),acc1); acc2=fmaf(w4,bf2f(h4.z),acc2); acc3=fmaf(w4,bf2f(h4.w),acc3); den+=w4;
    acc0=fmaf(w5,bf2f(h5.x),acc0); acc1=fmaf(w5,bf2f(h5.y),acc1); acc2=fmaf(w5,bf2f(h5.z),acc2); acc3=fmaf(w5,bf2f(h5.w),acc3); den+=w5;
    acc0=fmaf(w6,bf2f(h6.x),acc0); acc1=fmaf(w6,bf2f(h6.y),acc1); acc2=fmaf(w6,bf2f(h6.z),acc2); acc3=fmaf(w6,bf2f(h6.w),acc3); den+=w6;
    acc0=fmaf(w7,bf2f(h7.x),acc0); acc1=fmaf(w7,bf2f(h7.y),acc1); acc2=fmaf(w7,bf2f(h7.z),acc2); acc3=fmaf(w7,bf2f(h7.w),acc3); den+=w7;
  }
  for (; e < r1; e += 2){
    int s = csr[e];
    float4 a4 = as_[s];
    float w = __expf(lrelu(sel4(hh,a4)+adh));
    ushort4 hv = *(const ushort4*)&hb[(size_t)s*128+4*cl];
    acc0=fmaf(w,bf2f(hv.x),acc0); acc1=fmaf(w,bf2f(hv.y),acc1); acc2=fmaf(w,bf2f(hv.z),acc2); acc3=fmaf(w,bf2f(hv.w),acc3); den+=w;
  }
  acc0 += __shfl_xor(acc0,32); acc1 += __shfl_xor(acc1,32);
  acc2 += __shfl_xor(acc2,32); acc3 += __shfl_xor(acc3,32);
  den  += __shfl_xor(den,32);
  if (half == 0){
    float inv = 1.0f/den;
    float4 bv = *(const float4*)&bias[4*cl];
    float4 o;
    o.x = fmaxf(fmaf(acc0,inv,bv.x), 0.f);
    o.y = fmaxf(fmaf(acc1,inv,bv.y), 0.f);
    o.z = fmaxf(fmaf(acc2,inv,bv.z), 0.f);
    o.w = fmaxf(fmaf(acc3,inv,bv.w), 0.f);
    *(float4*)&hout[(size_t)d*128 + 4*cl] = o;
  }
}

// ---------------- aggregation layer 3 (1 head x 32 ch) + fused final linear ----------------
__global__ __launch_bounds__(256) void agg_h1_lin(const unsigned short* __restrict__ hb,
    const float* __restrict__ as_, const float* __restrict__ ad_,
    const int* __restrict__ offs, const int* __restrict__ csr,
    const float* __restrict__ b3, const float* __restrict__ Wlin, const float* __restrict__ blin,
    float* __restrict__ out, int n){
  int wid = (blockIdx.x*256 + threadIdx.x) >> 6;
  int lane = threadIdx.x & 63;
  if (wid >= n) return;
  const int d = wid;
  float add = ad_[d];
  float asd = as_[d];
  int r0 = offs[d], r1 = offs[d+1];
  int half = lane >> 5;
  int c = lane & 31;
  float acc=0.f, den=0.f;
  if (half == 0){
    float w = __expf(lrelu(asd+add));
    acc = w*bf2f(hb[(size_t)d*32 + c]); den = w;
  }
  int e = r0 + half;
  for (; e+14 < r1; e += 16){
    int s0=csr[e],   s1=csr[e+2],  s2=csr[e+4],  s3=csr[e+6];
    int s4=csr[e+8], s5=csr[e+10], s6=csr[e+12], s7=csr[e+14];
    float a0=as_[s0], a1=as_[s1], a2=as_[s2], a3=as_[s3];
    float a4=as_[s4], a5=as_[s5], a6=as_[s6], a7=as_[s7];
    float v0=bf2f(hb[(size_t)s0*32+c]), v1=bf2f(hb[(size_t)s1*32+c]);
    float v2=bf2f(hb[(size_t)s2*32+c]), v3=bf2f(hb[(size_t)s3*32+c]);
    float v4=bf2f(hb[(size_t)s4*32+c]), v5=bf2f(hb[(size_t)s5*32+c]);
    float v6=bf2f(hb[(size_t)s6*32+c]), v7=bf2f(hb[(size_t)s7*32+c]);
    float w0=__expf(lrelu(a0+add)), w1=__expf(lrelu(a1+add));
    float w2=__expf(lrelu(a2+add)), w3=__expf(lrelu(a3+add));
    float w4=__expf(lrelu(a4+add)), w5=__expf(lrelu(a5+add));
    float w6=__expf(lrelu(a6+add)), w7=__expf(lrelu(a7+add));
    acc=fmaf(w0,v0,acc); den+=w0;
    acc=fmaf(w1,v1,acc); den+=w1;
    acc=fmaf(w2,v2,acc); den+=w2;
    acc=fmaf(w3,v3,acc); den+=w3;
    acc=fmaf(w4,v4,acc); den+=w4;
    acc=fmaf(w5,v5,acc); den+=w5;
    acc=fmaf(w6,v6,acc); den+=w6;
    acc=fmaf(w7,v7,acc); den+=w7;
  }
  for (; e < r1; e += 2){
    int s = csr[e];
    float w=__expf(lrelu(as_[s]+add));
    acc=fmaf(w,bf2f(hb[(size_t)s*32+c]),acc); den+=w;
  }
  acc += __shfl_xor(acc,32);
  den += __shfl_xor(den,32);
  float v = fmaxf(acc/den + b3[c], 0.f);
  float y0 = v*Wlin[c*2+0];
  float y1 = v*Wlin[c*2+1];
  #pragma unroll
  for (int mk=16; mk>=1; mk>>=1){ y0 += __shfl_xor(y0,mk); y1 += __shfl_xor(y1,mk); }
  if (lane==0){ out[(size_t)d*2+0] = y0 + blin[0]; out[(size_t)d*2+1] = y1 + blin[1]; }
}

extern "C" void kernel_launch(void* const* d_in, const int* in_sizes, int n_in,
                              void* d_out, int out_size, void* d_ws, size_t ws_size,
                              hipStream_t stream){
  const int N = in_sizes[0] / 128;     // 50000
  const int E = in_sizes[1] / 2;       // 1600000
  const float* x    = (const float*)d_in[0];
  const int*   ei   = (const int*)d_in[1];
  const int*   srcv = ei;
  const int*   dstv = ei + E;
  const float* W1 = (const float*)d_in[2];
  const float* a1s= (const float*)d_in[3];
  const float* a1d= (const float*)d_in[4];
  const float* b1 = (const float*)d_in[5];
  const float* W2 = (const float*)d_in[6];
  const float* a2s= (const float*)d_in[7];
  const float* a2d= (const float*)d_in[8];
  const float* b2 = (const float*)d_in[9];
  const float* W3 = (const float*)d_in[10];
  const float* a3s= (const float*)d_in[11];
  const float* a3d= (const float*)d_in[12];
  const float* b3 = (const float*)d_in[13];
  const float* Wlin=(const float*)d_in[14];
  const float* blin=(const float*)d_in[15];
  float* out = (float*)d_out;

  const int NB = (N + 255) >> BSH;     // 256-node buckets

  char* wp = (char*)d_ws;
  auto alloc = [&](size_t bytes)->void*{
    void* p = (void*)wp;
    wp += (bytes + 255) & ~(size_t)255;
    return p;
  };
  float* h     = (float*)alloc((size_t)N*128*4);   // fp32 agg output (gemm input)
  unsigned short* hb = (unsigned short*)alloc((size_t)N*128*2);
  float* as_   = (float*)alloc((size_t)N*4*4);
  float* ad_   = (float*)alloc((size_t)N*4*4);
  int*   offs  = (int*)alloc((size_t)(N+1)*4);
  int*   csr   = (int*)alloc((size_t)E*4);
  int*   bcnt  = (int*)alloc((size_t)NB*4);
  int*   bbase = (int*)alloc((size_t)(NB+1)*4);
  int*   bcur  = (int*)alloc((size_t)NB*4);
  int2*  pairs = (int2*)h;             // alias: h is dead during CSR build

  const int gridB = (E + CHB - 1)/CHB; // binning blocks
  const int gridW = (N + 3)/4;         // wave-per-node kernels

  // CSR build: block-staged bucket sort
  zero_kernel<<<1, 256, 0, stream>>>(bcnt, NB);
  bin_count<<<gridB, 256, 0, stream>>>(dstv, bcnt, E, NB);
  scan_kernel<<<1, 256, 0, stream>>>(bcnt, bbase, bcur, NB);
  bin_scatter<<<gridB, 256, 0, stream>>>(srcv, dstv, bcur, pairs, E, NB);
  bucket_finalize<<<NB, 256, 0, stream>>>(pairs, bbase, offs, csr, N, E);

  // Layer 1  (BM=32 -> 1563 blocks, 16KB LDS -> high occupancy)
  gemm_fused<128,2,4><<<(N+31)/32, 256, 0, stream>>>(x, W1, a1s, a1d, hb, as_, ad_, N);
  agg_h4<<<gridW, 256, 0, stream>>>(hb, (const float4*)as_, (const float4*)ad_, offs, csr, b1, h, N);

  // Layer 2
  gemm_fused<128,2,4><<<(N+31)/32, 256, 0, stream>>>(h, W2, a2s, a2d, hb, as_, ad_, N);
  agg_h4<<<gridW, 256, 0, stream>>>(hb, (const float4*)as_, (const float4*)ad_, offs, csr, b2, h, N);

  // Layer 3 (32 out, BM=64 -> 782 blocks, 16KB LDS single chunk) + fused final linear
  gemm_fused<32,1,1><<<(N+63)/64, 256, 0, stream>>>(h, W3, a3s, a3d, hb, as_, ad_, N);
  agg_h1_lin<<<gridW, 256, 0, stream>>>(hb, as_, ad_, offs, csr, b3, Wlin, blin, out, N);
}

// Round 14
// 427.970 us; speedup vs baseline: 1.9684x; 1.9684x over previous
//
#include <hip/hip_runtime.h>

#define NEG 0.2f
#define BSH 8                       // 256 nodes per bucket
#define CHB 8192                    // edges per binning block
__device__ __forceinline__ float lrelu(float x){ return fmaxf(x, NEG*x); }

__device__ __forceinline__ float bf2f(unsigned short u){
  union{unsigned int i; float f;} v; v.i = ((unsigned int)u)<<16; return v.f;
}
__device__ __forceinline__ unsigned short f2bf(float f){
  union{float f; unsigned int i;} v; v.f = f;
  unsigned int b = v.i;
  b += 0x7FFFu + ((b>>16)&1u);   // round-to-nearest-even
  return (unsigned short)(b>>16);
}

// ---------------- CSR build: block-staged two-level counting sort ----------------
__global__ __launch_bounds__(256) void zero_kernel(int* __restrict__ p, int n){
  int i = blockIdx.x*256 + threadIdx.x;
  if (i < n) p[i] = 0;
}

__global__ __launch_bounds__(256) void bin_count(const int* __restrict__ dstv, int* __restrict__ bcnt,
                                                 int E, int NB){
  __shared__ int lh[256];
  int tid = threadIdx.x;
  lh[tid] = 0;
  __syncthreads();
  int e0 = blockIdx.x * CHB;
  int e1 = min(e0 + CHB, E);
  for (int i = e0 + tid; i < e1; i += 256)
    atomicAdd(&lh[dstv[i] >> BSH], 1);
  __syncthreads();
  if (tid < NB && lh[tid] > 0) atomicAdd(&bcnt[tid], lh[tid]);
}

__global__ __launch_bounds__(256) void scan_kernel(const int* __restrict__ counts, int* __restrict__ offs,
                                                   int* __restrict__ cursor, int n){
  __shared__ int wsum[4];
  __shared__ int carry_s;
  int tid = threadIdx.x, lane = tid & 63, wv = tid >> 6;
  if (tid == 0) carry_s = 0;
  __syncthreads();
  const int CH = 2048;
  int nch = (n + CH - 1)/CH;
  for (int ch=0; ch<nch; ++ch){
    int base_i = ch*CH + tid*8;
    int v[8], pre[8];
    #pragma unroll
    for (int j=0;j<8;++j){ int i=base_i+j; v[j]=(i<n)?counts[i]:0; }
    int t=0;
    #pragma unroll
    for (int j=0;j<8;++j){ pre[j]=t; t+=v[j]; }
    int incl=t;
    #pragma unroll
    for (int m=1;m<64;m<<=1){ int u=__shfl_up(incl,m); if(lane>=m) incl+=u; }
    int wexcl = incl - t;
    if (lane==63) wsum[wv]=incl;
    __syncthreads();
    int wbase=0;
    for (int w2=0;w2<wv;++w2) wbase+=wsum[w2];
    int total = wsum[0]+wsum[1]+wsum[2]+wsum[3];
    int base = carry_s + wbase + wexcl;
    #pragma unroll
    for (int j=0;j<8;++j){ int i=base_i+j; if(i<n){ int val=base+pre[j]; offs[i]=val; cursor[i]=val; } }
    __syncthreads();
    if (tid==0) carry_s += total;
    __syncthreads();
  }
  if (tid==0) offs[n]=carry_s;
}

// pairs packed: (src << 8) | (dst & 255)   [src < 2^24, 256-node buckets]
__global__ __launch_bounds__(256) void bin_scatter(const int* __restrict__ srcv, const int* __restrict__ dstv,
                                                   int* __restrict__ bcur, int* __restrict__ pairs,
                                                   int E, int NB){
  __shared__ int lh[256];
  __shared__ int lcur[256];
  int tid = threadIdx.x;
  lh[tid] = 0;
  __syncthreads();
  int e0 = blockIdx.x * CHB;
  int e1 = min(e0 + CHB, E);
  for (int i = e0 + tid; i < e1; i += 256)
    atomicAdd(&lh[dstv[i] >> BSH], 1);
  __syncthreads();
  if (tid < NB){
    int c = lh[tid];
    lcur[tid] = (c > 0) ? atomicAdd(&bcur[tid], c) : 0;
  }
  __syncthreads();
  for (int i = e0 + tid; i < e1; i += 256){
    int s = srcv[i], d = dstv[i];
    int p = atomicAdd(&lcur[d >> BSH], 1);
    pairs[p] = (s << 8) | (d & 255);
  }
}

__global__ __launch_bounds__(256) void bucket_finalize(const int* __restrict__ pairs,
                                                       const int* __restrict__ bbase,
                                                       int* __restrict__ offs, int* __restrict__ csr,
                                                       int N, int E){
  __shared__ int lh[256];
  __shared__ int lcur[256];
  __shared__ int wsum[4];
  int b = blockIdx.x;
  int base = bbase[b], end = bbase[b+1];
  int node0 = b << BSH;
  int tid = threadIdx.x, lane = tid & 63, wv = tid >> 6;
  lh[tid] = 0;
  if (b == 0 && tid == 0) offs[N] = E;
  __syncthreads();
  for (int i = base + tid; i < end; i += 256)
    atomicAdd(&lh[pairs[i] & 255], 1);
  __syncthreads();
  {
    int v = lh[tid];
    int incl = v;
    #pragma unroll
    for (int m=1;m<64;m<<=1){ int u=__shfl_up(incl,m); if(lane>=m) incl+=u; }
    if (lane==63) wsum[wv]=incl;
    __syncthreads();
    int wbase=0;
    for (int w2=0;w2<wv;++w2) wbase+=wsum[w2];
    int excl = wbase + incl - v;
    lcur[tid] = base + excl;
    int node = node0 + tid;
    if (node < N) offs[node] = base + excl;
  }
  __syncthreads();
  for (int i = base + tid; i < end; i += 256){
    int pr = pairs[i];
    int p = atomicAdd(&lcur[pr & 255], 1);
    csr[p] = pr >> 8;
  }
}

// ---------------- GEMM fused with alpha dots + bf16 cast ----------------
// single-buffered chunked W staging (32KB LDS max), TR rows/thread, dynamic chunk loop
// NOTE: codegen-stable point (52 VGPR): CHK=64 for NOUT=128, TR=4. Do not perturb.
template<int NOUT, int TR, int HEADS>
__global__ __launch_bounds__(256) void gemm_fused(const float* __restrict__ X, const float* __restrict__ W,
    const float* __restrict__ a_s, const float* __restrict__ a_d,
    unsigned short* __restrict__ hb, float* __restrict__ as_, float* __restrict__ ad_, int n){
  constexpr int NC = NOUT / 8;          // threads per row
  constexpr int RG = 256 / NC;          // row groups
  constexpr int BM = RG * TR;           // rows per block
  constexpr int CHK = (NOUT > 64) ? 64 : 128;   // k rows per chunk (<=32KB LDS)
  constexpr int NCH = 128 / CHK;
  __shared__ float Wl[CHK * NOUT];
  int tid = threadIdx.x;
  int cg = tid % NC;
  int rg = tid / NC;
  int lane = tid & 63;
  int row0 = blockIdx.x * BM + rg * TR;
  const float4* Wv = (const float4*)W;
  const float4* Xv = (const float4*)X;
  float acc[TR][8];
  #pragma unroll
  for (int r=0;r<TR;++r)
    #pragma unroll
    for (int c=0;c<8;++c) acc[r][c]=0.f;
  for (int ch = 0; ch < NCH; ++ch){
    if (ch) __syncthreads();
    for (int i = tid; i < CHK*NOUT/4; i += 256)
      ((float4*)Wl)[i] = Wv[ch*(CHK*NOUT/4) + i];
    __syncthreads();
    for (int k4i = 0; k4i < CHK/4; ++k4i){
      int k4 = ch*(CHK/4) + k4i;
      float4 xv[TR];
      #pragma unroll
      for (int r = 0; r < TR; ++r){
        int row = row0 + r;
        xv[r] = (row < n) ? Xv[(size_t)row*32 + k4] : make_float4(0.f,0.f,0.f,0.f);
      }
      #pragma unroll
      for (int kk = 0; kk < 4; ++kk){
        float wv[8];
        #pragma unroll
        for (int c = 0; c < 8; ++c) wv[c] = Wl[(k4i*4+kk)*NOUT + cg*8 + c];
        #pragma unroll
        for (int r = 0; r < TR; ++r){
          float xr = (kk==0)?xv[r].x:(kk==1)?xv[r].y:(kk==2)?xv[r].z:xv[r].w;
          #pragma unroll
          for (int c = 0; c < 8; ++c) acc[r][c] = fmaf(xr, wv[c], acc[r][c]);
        }
      }
    }
  }
  // epilogue: bf16 row + per-head alpha dots (head = 32 ch = 4 threads)
  float asl[8], adl[8];
  #pragma unroll
  for (int c=0;c<8;++c){ asl[c]=a_s[cg*8+c]; adl[c]=a_d[cg*8+c]; }
  #pragma unroll
  for (int r = 0; r < TR; ++r){
    int row = row0 + r;
    float s=0.f, dd=0.f;
    #pragma unroll
    for (int c=0;c<8;++c){ s = fmaf(acc[r][c], asl[c], s); dd = fmaf(acc[r][c], adl[c], dd); }
    s  += __shfl_xor(s,1);  s  += __shfl_xor(s,2);
    dd += __shfl_xor(dd,1); dd += __shfl_xor(dd,2);
    if (HEADS == 4){
      int base = lane & ~15;
      float s0=__shfl(s,base),  s1=__shfl(s,base+4),  s2=__shfl(s,base+8),  s3=__shfl(s,base+12);
      float d0=__shfl(dd,base), d1=__shfl(dd,base+4), d2=__shfl(dd,base+8), d3=__shfl(dd,base+12);
      if (row < n && cg == 0){
        ((float4*)as_)[row] = make_float4(s0,s1,s2,s3);
        ((float4*)ad_)[row] = make_float4(d0,d1,d2,d3);
      }
    } else {
      if (row < n && (lane&3) == 0){ as_[row] = s; ad_[row] = dd; }
    }
    if (row < n){
      ushort4 p0, p1;
      p0.x=f2bf(acc[r][0]); p0.y=f2bf(acc[r][1]); p0.z=f2bf(acc[r][2]); p0.w=f2bf(acc[r][3]);
      p1.x=f2bf(acc[r][4]); p1.y=f2bf(acc[r][5]); p1.z=f2bf(acc[r][6]); p1.w=f2bf(acc[r][7]);
      *(ushort4*)&hb[(size_t)row*NOUT + cg*8 + 0] = p0;
      *(ushort4*)&hb[(size_t)row*NOUT + cg*8 + 4] = p1;
    }
  }
}

__device__ __forceinline__ float sel4(int hh, float4 v){
  return (hh&2) ? ((hh&1)?v.w:v.z) : ((hh&1)?v.y:v.x);
}

// ---------------- aggregation, 4 heads x 32 ch: half-wave per edge, bf16 messages ----------------
__global__ __launch_bounds__(256) void agg_h4(const unsigned short* __restrict__ hb,
    const float4* __restrict__ as_, const float4* __restrict__ ad_,
    const int* __restrict__ offs, const int* __restrict__ csr,
    const float* __restrict__ bias, float* __restrict__ hout, int n){
  int wid = (blockIdx.x*256 + threadIdx.x) >> 6;
  int lane = threadIdx.x & 63;
  if (wid >= n) return;
  const int d = wid;
  float4 ad4 = ad_[d];
  float4 asd = as_[d];
  int r0 = offs[d], r1 = offs[d+1];
  int half = lane >> 5;
  int cl = lane & 31;        // channel group -> 4 channels
  int hh = cl >> 3;          // head
  float adh = sel4(hh, ad4);
  float asv = sel4(hh, asd);
  float acc0=0.f, acc1=0.f, acc2=0.f, acc3=0.f, den=0.f;
  if (half == 0){
    float w = __expf(lrelu(asv+adh));
    ushort4 hv = *(const ushort4*)&hb[(size_t)d*128 + 4*cl];
    acc0 = w*bf2f(hv.x); acc1 = w*bf2f(hv.y); acc2 = w*bf2f(hv.z); acc3 = w*bf2f(hv.w); den = w;
  }
  int e = r0 + half;
  for (; e+14 < r1; e += 16){
    int s0=csr[e],   s1=csr[e+2],  s2=csr[e+4],  s3=csr[e+6];
    int s4=csr[e+8], s5=csr[e+10], s6=csr[e+12], s7=csr[e+14];
    float4 a0=as_[s0], a1=as_[s1], a2=as_[s2], a3=as_[s3];
    float4 a4=as_[s4], a5=as_[s5], a6=as_[s6], a7=as_[s7];
    ushort4 h0=*(const ushort4*)&hb[(size_t)s0*128+4*cl];
    ushort4 h1=*(const ushort4*)&hb[(size_t)s1*128+4*cl];
    ushort4 h2=*(const ushort4*)&hb[(size_t)s2*128+4*cl];
    ushort4 h3=*(const ushort4*)&hb[(size_t)s3*128+4*cl];
    ushort4 h4=*(const ushort4*)&hb[(size_t)s4*128+4*cl];
    ushort4 h5=*(const ushort4*)&hb[(size_t)s5*128+4*cl];
    ushort4 h6=*(const ushort4*)&hb[(size_t)s6*128+4*cl];
    ushort4 h7=*(const ushort4*)&hb[(size_t)s7*128+4*cl];
    float w0=__expf(lrelu(sel4(hh,a0)+adh));
    float w1=__expf(lrelu(sel4(hh,a1)+adh));
    float w2=__expf(lrelu(sel4(hh,a2)+adh));
    float w3=__expf(lrelu(sel4(hh,a3)+adh));
    float w4=__expf(lrelu(sel4(hh,a4)+adh));
    float w5=__expf(lrelu(sel4(hh,a5)+adh));
    float w6=__expf(lrelu(sel4(hh,a6)+adh));
    float w7=__expf(lrelu(sel4(hh,a7)+adh));
    acc0=fmaf(w0,bf2f(h0.x),acc0); acc1=fmaf(w0,bf2f(h0.y),acc1); acc2=fmaf(w0,bf2f(h0.z),acc2); acc3=fmaf(w0,bf2f(h0.w),acc3); den+=w0;
    acc0=fmaf(w1,bf2f(h1.x),acc0); acc1=fmaf(w1,bf2f(h1.y),acc1); acc2=fmaf(w1,bf2f(h1.z),acc2); acc3=fmaf(w1,bf2f(h1.w),acc3); den+=w1;
    acc0=fmaf(w2,bf2f(h2.x),acc0); acc1=fmaf(w2,bf2f(h2.y),acc1); acc2=fmaf(w2,bf2f(h2.z),acc2); acc3=fmaf(w2,bf2f(h2.w),acc3); den+=w2;
    acc0=fmaf(w3,bf2f(h3.x),acc0); acc1=fmaf(w3,bf2f(h3.y),acc1); acc2=fmaf(w3,bf2f(h3.z),acc2); acc3=fmaf(w3,bf2f(h3.w),acc3); den+=w3;
    acc0=fmaf(w4,bf2f(h4.x),acc0); acc1=fmaf(w4,bf2f(h4.y),acc1); acc2=fmaf(w4,bf2f(h4.z),acc2); acc3=fmaf(w4,bf2f(h4.w),acc3); den+=w4;
    acc0=fmaf(w5,bf2f(h5.x),acc0); acc1=fmaf(w5,bf2f(h5.y),acc1); acc2=fmaf(w5,bf2f(h5.z),acc2); acc3=fmaf(w5,bf2f(h5.w),acc3); den+=w5;
    acc0=fmaf(w6,bf2f(h6.x),acc0); acc1=fmaf(w6,bf2f(h6.y),acc1); acc2=fmaf(w6,bf2f(h6.z),acc2); acc3=fmaf(w6,bf2f(h6.w),acc3); den+=w6;
    acc0=fmaf(w7,bf2f(h7.x),acc0); acc1=fmaf(w7,bf2f(h7.y),acc1); acc2=fmaf(w7,bf2f(h7.z),acc2); acc3=fmaf(w7,bf2f(h7.w),acc3); den+=w7;
  }
  for (; e < r1; e += 2){
    int s = csr[e];
    float4 a4 = as_[s];
    float w = __expf(lrelu(sel4(hh,a4)+adh));
    ushort4 hv = *(const ushort4*)&hb[(size_t)s*128+4*cl];
    acc0=fmaf(w,bf2f(hv.x),acc0); acc1=fmaf(w,bf2f(hv.y),acc1); acc2=fmaf(w,bf2f(hv.z),acc2); acc3=fmaf(w,bf2f(hv.w),acc3); den+=w;
  }
  acc0 += __shfl_xor(acc0,32); acc1 += __shfl_xor(acc1,32);
  acc2 += __shfl_xor(acc2,32); acc3 += __shfl_xor(acc3,32);
  den  += __shfl_xor(den,32);
  if (half == 0){
    float inv = 1.0f/den;
    float4 bv = *(const float4*)&bias[4*cl];
    float4 o;
    o.x = fmaxf(fmaf(acc0,inv,bv.x), 0.f);
    o.y = fmaxf(fmaf(acc1,inv,bv.y), 0.f);
    o.z = fmaxf(fmaf(acc2,inv,bv.z), 0.f);
    o.w = fmaxf(fmaf(acc3,inv,bv.w), 0.f);
    *(float4*)&hout[(size_t)d*128 + 4*cl] = o;
  }
}

// ---------------- aggregation layer 3 (1 head x 32 ch) + fused final linear ----------------
__global__ __launch_bounds__(256) void agg_h1_lin(const unsigned short* __restrict__ hb,
    const float* __restrict__ as_, const float* __restrict__ ad_,
    const int* __restrict__ offs, const int* __restrict__ csr,
    const float* __restrict__ b3, const float* __restrict__ Wlin, const float* __restrict__ blin,
    float* __restrict__ out, int n){
  int wid = (blockIdx.x*256 + threadIdx.x) >> 6;
  int lane = threadIdx.x & 63;
  if (wid >= n) return;
  const int d = wid;
  float add = ad_[d];
  float asd = as_[d];
  int r0 = offs[d], r1 = offs[d+1];
  int half = lane >> 5;
  int c = lane & 31;
  float acc=0.f, den=0.f;
  if (half == 0){
    float w = __expf(lrelu(asd+add));
    acc = w*bf2f(hb[(size_t)d*32 + c]); den = w;
  }
  int e = r0 + half;
  for (; e+14 < r1; e += 16){
    int s0=csr[e],   s1=csr[e+2],  s2=csr[e+4],  s3=csr[e+6];
    int s4=csr[e+8], s5=csr[e+10], s6=csr[e+12], s7=csr[e+14];
    float a0=as_[s0], a1=as_[s1], a2=as_[s2], a3=as_[s3];
    float a4=as_[s4], a5=as_[s5], a6=as_[s6], a7=as_[s7];
    float v0=bf2f(hb[(size_t)s0*32+c]), v1=bf2f(hb[(size_t)s1*32+c]);
    float v2=bf2f(hb[(size_t)s2*32+c]), v3=bf2f(hb[(size_t)s3*32+c]);
    float v4=bf2f(hb[(size_t)s4*32+c]), v5=bf2f(hb[(size_t)s5*32+c]);
    float v6=bf2f(hb[(size_t)s6*32+c]), v7=bf2f(hb[(size_t)s7*32+c]);
    float w0=__expf(lrelu(a0+add)), w1=__expf(lrelu(a1+add));
    float w2=__expf(lrelu(a2+add)), w3=__expf(lrelu(a3+add));
    float w4=__expf(lrelu(a4+add)), w5=__expf(lrelu(a5+add));
    float w6=__expf(lrelu(a6+add)), w7=__expf(lrelu(a7+add));
    acc=fmaf(w0,v0,acc); den+=w0;
    acc=fmaf(w1,v1,acc); den+=w1;
    acc=fmaf(w2,v2,acc); den+=w2;
    acc=fmaf(w3,v3,acc); den+=w3;
    acc=fmaf(w4,v4,acc); den+=w4;
    acc=fmaf(w5,v5,acc); den+=w5;
    acc=fmaf(w6,v6,acc); den+=w6;
    acc=fmaf(w7,v7,acc); den+=w7;
  }
  for (; e < r1; e += 2){
    int s = csr[e];
    float w=__expf(lrelu(as_[s]+add));
    acc=fmaf(w,bf2f(hb[(size_t)s*32+c]),acc); den+=w;
  }
  acc += __shfl_xor(acc,32);
  den += __shfl_xor(den,32);
  float v = fmaxf(acc/den + b3[c], 0.f);
  float y0 = v*Wlin[c*2+0];
  float y1 = v*Wlin[c*2+1];
  #pragma unroll
  for (int mk=16; mk>=1; mk>>=1){ y0 += __shfl_xor(y0,mk); y1 += __shfl_xor(y1,mk); }
  if (lane==0){ out[(size_t)d*2+0] = y0 + blin[0]; out[(size_t)d*2+1] = y1 + blin[1]; }
}

extern "C" void kernel_launch(void* const* d_in, const int* in_sizes, int n_in,
                              void* d_out, int out_size, void* d_ws, size_t ws_size,
                              hipStream_t stream){
  const int N = in_sizes[0] / 128;     // 50000
  const int E = in_sizes[1] / 2;       // 1600000
  const float* x    = (const float*)d_in[0];
  const int*   ei   = (const int*)d_in[1];
  const int*   srcv = ei;
  const int*   dstv = ei + E;
  const float* W1 = (const float*)d_in[2];
  const float* a1s= (const float*)d_in[3];
  const float* a1d= (const float*)d_in[4];
  const float* b1 = (const float*)d_in[5];
  const float* W2 = (const float*)d_in[6];
  const float* a2s= (const float*)d_in[7];
  const float* a2d= (const float*)d_in[8];
  const float* b2 = (const float*)d_in[9];
  const float* W3 = (const float*)d_in[10];
  const float* a3s= (const float*)d_in[11];
  const float* a3d= (const float*)d_in[12];
  const float* b3 = (const float*)d_in[13];
  const float* Wlin=(const float*)d_in[14];
  const float* blin=(const float*)d_in[15];
  float* out = (float*)d_out;

  const int NB = (N + 255) >> BSH;     // 256-node buckets

  char* wp = (char*)d_ws;
  auto alloc = [&](size_t bytes)->void*{
    void* p = (void*)wp;
    wp += (bytes + 255) & ~(size_t)255;
    return p;
  };
  float* h     = (float*)alloc((size_t)N*128*4);   // fp32 agg output (gemm input)
  unsigned short* hb = (unsigned short*)alloc((size_t)N*128*2);
  float* as_   = (float*)alloc((size_t)N*4*4);
  float* ad_   = (float*)alloc((size_t)N*4*4);
  int*   offs  = (int*)alloc((size_t)(N+1)*4);
  int*   csr   = (int*)alloc((size_t)E*4);
  int*   bcnt  = (int*)alloc((size_t)NB*4);
  int*   bbase = (int*)alloc((size_t)(NB+1)*4);
  int*   bcur  = (int*)alloc((size_t)NB*4);
  int*   pairs = (int*)h;              // alias: h is dead during CSR build

  const int gridB = (E + CHB - 1)/CHB; // binning blocks
  const int gridW = (N + 3)/4;         // wave-per-node kernels

  // CSR build: block-staged bucket sort (packed pairs: src<<8 | localdst)
  zero_kernel<<<1, 256, 0, stream>>>(bcnt, NB);
  bin_count<<<gridB, 256, 0, stream>>>(dstv, bcnt, E, NB);
  scan_kernel<<<1, 256, 0, stream>>>(bcnt, bbase, bcur, NB);
  bin_scatter<<<gridB, 256, 0, stream>>>(srcv, dstv, bcur, pairs, E, NB);
  bucket_finalize<<<NB, 256, 0, stream>>>(pairs, bbase, offs, csr, N, E);

  // Layer 1  (BM = 64 rows/block -> 782 blocks, 32KB LDS)
  gemm_fused<128,4,4><<<(N+63)/64, 256, 0, stream>>>(x, W1, a1s, a1d, hb, as_, ad_, N);
  agg_h4<<<gridW, 256, 0, stream>>>(hb, (const float4*)as_, (const float4*)ad_, offs, csr, b1, h, N);

  // Layer 2
  gemm_fused<128,4,4><<<(N+63)/64, 256, 0, stream>>>(h, W2, a2s, a2d, hb, as_, ad_, N);
  agg_h4<<<gridW, 256, 0, stream>>>(hb, (const float4*)as_, (const float4*)ad_, offs, csr, b2, h, N);

  // Layer 3 (32 out, BM = 256 -> 196 blocks, 16KB LDS single chunk) + fused final linear
  gemm_fused<32,4,1><<<(N+255)/256, 256, 0, stream>>>(h, W3, a3s, a3d, hb, as_, ad_, N);
  agg_h1_lin<<<gridW, 256, 0, stream>>>(hb, as_, ad_, offs, csr, b3, Wlin, blin, out, N);
}